// Round 1
// baseline (404.997 us; speedup 1.0000x reference)
//
#include <hip/hip_runtime.h>
#include <hip/hip_bf16.h>

typedef unsigned short u16;
typedef __attribute__((ext_vector_type(8))) short short8;
typedef __attribute__((ext_vector_type(8))) unsigned short ushort8;
typedef __attribute__((ext_vector_type(4))) float f32x4;

typedef __attribute__((address_space(1))) void gvoid_t;
typedef __attribute__((address_space(3))) void lvoid_t;

__device__ __forceinline__ void gload_lds16(const void* g, void* l) {
    __builtin_amdgcn_global_load_lds((gvoid_t*)g, (lvoid_t*)l, 16, 0, 0);
}

// fp32 -> bf16 RNE, bit-level (avoids header API differences)
__device__ __forceinline__ u16 f2bf(float f) {
    union { float f; unsigned int u; } v; v.f = f;
    unsigned int u = v.u;
    unsigned int r = (u + 0x7FFFu + ((u >> 16) & 1u)) >> 16;
    return (u16)r;
}

// sign(w) as bf16 bits: +1.0 = 0x3F80, -1.0 = 0xBF80, 0 -> 0
__device__ __forceinline__ u16 sgnbits(float v) {
    return v > 0.f ? (u16)0x3F80 : (v < 0.f ? (u16)0xBF80 : (u16)0);
}

// ---------------- pre-pass 1: x (M*K fp32) -> bf16, layout unchanged ----------------
__global__ __launch_bounds__(256) void cvt_x_kernel(const float* __restrict__ x,
                                                    u16* __restrict__ xb, long n8) {
    long i = (long)blockIdx.x * blockDim.x + threadIdx.x;
    if (i >= n8) return;
    const float4* p = (const float4*)(x + i * 8);
    float4 f0 = p[0], f1 = p[1];
    ushort8 o;
    o[0] = f2bf(f0.x); o[1] = f2bf(f0.y); o[2] = f2bf(f0.z); o[3] = f2bf(f0.w);
    o[4] = f2bf(f1.x); o[5] = f2bf(f1.y); o[6] = f2bf(f1.z); o[7] = f2bf(f1.w);
    *(ushort8*)(xb + i * 8) = o;
}

// ------ pre-pass 2: w (K x N fp32, row-major) -> Bt (N x K bf16 of sign(w)) ------
// 64x64 tile transpose through LDS.
__global__ __launch_bounds__(256) void binw_kernel(const float* __restrict__ w,
                                                   u16* __restrict__ bt,
                                                   int K, int N) {
    __shared__ u16 tile[64][72];   // +8 pad to dodge bank conflicts
    int n0 = blockIdx.x * 64;
    int k0 = blockIdx.y * 64;
    int t  = threadIdx.x;          // 0..255
    int cr = t >> 4;               // 0..15
    int cc = (t & 15) << 2;        // 0,4,...,60

    #pragma unroll
    for (int i = 0; i < 4; i++) {
        int r = cr + i * 16;       // k-local
        float4 v = *(const float4*)(w + (long)(k0 + r) * N + n0 + cc);
        ushort4 s;
        s.x = sgnbits(v.x); s.y = sgnbits(v.y); s.z = sgnbits(v.z); s.w = sgnbits(v.w);
        *(ushort4*)&tile[r][cc] = s;
    }
    __syncthreads();
    #pragma unroll
    for (int i = 0; i < 4; i++) {
        int nl = cr + i * 16;      // n-local
        ushort4 o;
        o.x = tile[cc + 0][nl];
        o.y = tile[cc + 1][nl];
        o.z = tile[cc + 2][nl];
        o.w = tile[cc + 3][nl];
        *(ushort4*)(bt + (long)(n0 + nl) * K + k0 + cc) = o;
    }
}

// ---------------- main GEMM: C(MxN,f32) = A(MxK,bf16) * Bt(NxK,bf16)^T * |g| ----------------
// m97 structure: 128x128 tile, BK=32, 4 waves (2x2), 4x4 16x16x32 MFMA frags/wave,
// global_load_lds width=16 staging, ds_read_b128 fragment loads.
#define BM 128
#define BN 128
#define BK 32

__global__ __launch_bounds__(256) void gemm_bin(const u16* __restrict__ A,
                                                const u16* __restrict__ Bt,
                                                const float* __restrict__ gp,
                                                float* __restrict__ C,
                                                int M, int N, int K) {
    __shared__ u16 As[BM * BK];   // 8 KB
    __shared__ u16 Bs[BN * BK];   // 8 KB

    int nwg = gridDim.x;
    int bid = blockIdx.x;
    // XCD-aware swizzle (valid: grid % 8 == 0)
    int swz = ((nwg & 7) == 0) ? ((bid & 7) * (nwg >> 3) + (bid >> 3)) : bid;
    int tiles_n = N / BN;
    int tm = swz / tiles_n;
    int tn = swz - tm * tiles_n;
    long brow = (long)tm * BM;
    long bcol = (long)tn * BN;

    int tid  = threadIdx.x;
    int lane = tid & 63;
    int wr = (tid >> 7) & 1;   // wave row (2x2 wave grid)
    int wc = (tid >> 6) & 1;   // wave col

    // staging: thread t loads 16B at tile row (t>>2), col (t&3)*8; second issue row+64
    const u16* a_src = A + (brow + (tid >> 2)) * (long)K + ((tid & 3) << 3);
    const u16* b_src = Bt + (bcol + (tid >> 2)) * (long)K + ((tid & 3) << 3);
    u16* as_dst = As + tid * 8;
    u16* bs_dst = Bs + tid * 8;

    // fragment element offsets (ushort units) into [128][32] LDS tiles
    int kcol = (lane >> 4) << 3;                       // 0,8,16,24
    int ar = ((wr << 6) | (lane & 15)) * BK + kcol;    // + m*16*BK
    int br = ((wc << 6) | (lane & 15)) * BK + kcol;    // + n*16*BK

    f32x4 acc[4][4];
    #pragma unroll
    for (int m = 0; m < 4; m++)
        #pragma unroll
        for (int n = 0; n < 4; n++)
            acc[m][n] = (f32x4){0.f, 0.f, 0.f, 0.f};

    for (int k0 = 0; k0 < K; k0 += BK) {
        gload_lds16(a_src,                as_dst);
        gload_lds16(a_src + 64 * (long)K, as_dst + 64 * BK);
        gload_lds16(b_src,                bs_dst);
        gload_lds16(b_src + 64 * (long)K, bs_dst + 64 * BK);
        a_src += BK;
        b_src += BK;
        __syncthreads();   // compiler emits vmcnt(0) drain before barrier

        short8 af[4], bf[4];
        #pragma unroll
        for (int m = 0; m < 4; m++) af[m] = *(const short8*)(As + ar + m * 16 * BK);
        #pragma unroll
        for (int n = 0; n < 4; n++) bf[n] = *(const short8*)(Bs + br + n * 16 * BK);
        #pragma unroll
        for (int m = 0; m < 4; m++)
            #pragma unroll
            for (int n = 0; n < 4; n++)
                acc[m][n] = __builtin_amdgcn_mfma_f32_16x16x32_bf16(af[m], bf[n], acc[m][n], 0, 0, 0);
        __syncthreads();
    }

    float g = fabsf(gp[0]);
    long crow = brow + (wr << 6) + ((lane >> 4) << 2);  // + m*16 + j
    long ccol = bcol + (wc << 6) + (lane & 15);         // + n*16
    #pragma unroll
    for (int m = 0; m < 4; m++)
        #pragma unroll
        for (int n = 0; n < 4; n++)
            #pragma unroll
            for (int j = 0; j < 4; j++)
                C[(crow + m * 16 + j) * (long)N + ccol + n * 16] = g * acc[m][n][j];
}

// ---------------- fallback (only if workspace is too small): naive fp32 ----------------
__global__ void fb_gemm(const float* __restrict__ x, const float* __restrict__ w,
                        const float* __restrict__ gp, float* __restrict__ out,
                        int M, int N, int K) {
    __shared__ float xs[16][17];
    __shared__ float ws[16][17];
    int tx = threadIdx.x, ty = threadIdx.y;
    long row = (long)blockIdx.y * 16 + ty;
    long col = (long)blockIdx.x * 16 + tx;
    float s = 0.f;
    for (int k0 = 0; k0 < K; k0 += 16) {
        xs[ty][tx] = x[row * K + k0 + tx];
        float wv = w[(long)(k0 + ty) * N + col];
        ws[ty][tx] = wv > 0.f ? 1.f : (wv < 0.f ? -1.f : 0.f);
        __syncthreads();
        #pragma unroll
        for (int kk = 0; kk < 16; kk++) s += xs[ty][kk] * ws[kk][tx];
        __syncthreads();
    }
    out[row * N + col] = fabsf(gp[0]) * s;
}

extern "C" void kernel_launch(void* const* d_in, const int* in_sizes, int n_in,
                              void* d_out, int out_size, void* d_ws, size_t ws_size,
                              hipStream_t stream) {
    const float* x  = (const float*)d_in[0];
    const float* w  = (const float*)d_in[1];
    const float* gp = (const float*)d_in[2];
    float* out = (float*)d_out;

    const int K = 4096, N = 4096;
    const int M = in_sizes[0] / K;   // 8192

    size_t need = ((size_t)M * K + (size_t)N * K) * sizeof(u16);  // 96 MiB
    if (ws_size >= need) {
        u16* xb = (u16*)d_ws;
        u16* bt = xb + (size_t)M * K;

        long n8 = (long)M * K / 8;
        cvt_x_kernel<<<(int)((n8 + 255) / 256), 256, 0, stream>>>(x, xb, n8);

        dim3 gt(N / 64, K / 64);
        binw_kernel<<<gt, 256, 0, stream>>>(w, bt, K, N);

        int grid = (M / BM) * (N / BN);   // 2048
        gemm_bin<<<grid, 256, 0, stream>>>(xb, bt, gp, out, M, N, K);
    } else {
        dim3 g(N / 16, M / 16), b(16, 16);
        fb_gemm<<<g, b, 0, stream>>>(x, w, gp, out, M, N, K);
    }
}

// Round 2
// 259.640 us; speedup vs baseline: 1.5598x; 1.5598x over previous
//
#include <hip/hip_runtime.h>
#include <hip/hip_bf16.h>

typedef unsigned short u16;
typedef __attribute__((ext_vector_type(8))) short short8;
typedef __attribute__((ext_vector_type(8))) unsigned short ushort8;
typedef __attribute__((ext_vector_type(4))) float f32x4;

typedef __attribute__((address_space(1))) void gvoid_t;
typedef __attribute__((address_space(3))) void lvoid_t;

__device__ __forceinline__ void gload_lds16(const void* g, void* l) {
    __builtin_amdgcn_global_load_lds((gvoid_t*)g, (lvoid_t*)l, 16, 0, 0);
}

__device__ __forceinline__ u16 f2bf(float f) {
    union { float f; unsigned int u; } v; v.f = f;
    unsigned int u = v.u;
    unsigned int r = (u + 0x7FFFu + ((u >> 16) & 1u)) >> 16;
    return (u16)r;
}

__device__ __forceinline__ u16 sgnbits(float v) {
    return v > 0.f ? (u16)0x3F80 : (v < 0.f ? (u16)0xBF80 : (u16)0);
}

// ---------------- pre-pass 1: x (M*K fp32) -> bf16 ----------------
__global__ __launch_bounds__(256) void cvt_x_kernel(const float* __restrict__ x,
                                                    u16* __restrict__ xb, long n8) {
    long i = (long)blockIdx.x * blockDim.x + threadIdx.x;
    if (i >= n8) return;
    const float4* p = (const float4*)(x + i * 8);
    float4 f0 = p[0], f1 = p[1];
    ushort8 o;
    o[0] = f2bf(f0.x); o[1] = f2bf(f0.y); o[2] = f2bf(f0.z); o[3] = f2bf(f0.w);
    o[4] = f2bf(f1.x); o[5] = f2bf(f1.y); o[6] = f2bf(f1.z); o[7] = f2bf(f1.w);
    *(ushort8*)(xb + i * 8) = o;
}

// ------ pre-pass 2: w (K x N fp32) -> Bt (N x K bf16 of sign(w)) ------
__global__ __launch_bounds__(256) void binw_kernel(const float* __restrict__ w,
                                                   u16* __restrict__ bt,
                                                   int K, int N) {
    __shared__ u16 tile[64][72];
    int n0 = blockIdx.x * 64;
    int k0 = blockIdx.y * 64;
    int t  = threadIdx.x;
    int cr = t >> 4;
    int cc = (t & 15) << 2;

    #pragma unroll
    for (int i = 0; i < 4; i++) {
        int r = cr + i * 16;
        float4 v = *(const float4*)(w + (long)(k0 + r) * N + n0 + cc);
        ushort4 s;
        s.x = sgnbits(v.x); s.y = sgnbits(v.y); s.z = sgnbits(v.z); s.w = sgnbits(v.w);
        *(ushort4*)&tile[r][cc] = s;
    }
    __syncthreads();
    #pragma unroll
    for (int i = 0; i < 4; i++) {
        int nl = cr + i * 16;
        ushort4 o;
        o.x = tile[cc + 0][nl];
        o.y = tile[cc + 1][nl];
        o.z = tile[cc + 2][nl];
        o.w = tile[cc + 3][nl];
        *(ushort4*)(bt + (long)(n0 + nl) * K + k0 + cc) = o;
    }
}

// ================= 256x256 8-phase GEMM (T1+T2+T3+T4+T5) =================
// C(MxN,f32) = A(MxK,bf16) * Bt(NxK,bf16)^T * |g|
// 8 waves (2M x 4N), BK=64, 2 K-tiles/iter, LDS 128KB:
//   A: [buf][half(128rows)][128][64]  at lds + buf*32768 + half*16384
//   B: same at lds + 65536 + ...
// T2 swizzle: phys_colbyte = logical_colbyte ^ ((row&7)<<4); gload_lds dest
// stays linear, global SOURCE is inverse-swizzled per lane (rule #21).

#define BARRIER() do{ __builtin_amdgcn_sched_barrier(0); __builtin_amdgcn_s_barrier(); __builtin_amdgcn_sched_barrier(0); }while(0)
#define WAIT_LGKM0() do{ asm volatile("s_waitcnt lgkmcnt(0)" ::: "memory"); __builtin_amdgcn_sched_barrier(0); }while(0)

__global__ __launch_bounds__(512, 2) void gemm_bin8(const u16* __restrict__ A,
                                                    const u16* __restrict__ Bt,
                                                    const float* __restrict__ gp,
                                                    float* __restrict__ C,
                                                    int M, int N, int K) {
    __shared__ __align__(16) char lds[131072];

    int nwg = gridDim.x;
    int bid = blockIdx.x;
    int swz = ((nwg & 7) == 0) ? ((bid & 7) * (nwg >> 3) + (bid >> 3)) : bid;
    int tiles_n = N >> 8;
    int tm = swz / tiles_n;
    int tn = swz - tm * tiles_n;
    long brow = (long)tm << 8;
    long bcol = (long)tn << 8;

    const int tid  = threadIdx.x;
    const int lane = tid & 63;
    const int wid  = tid >> 6;
    const int wr = wid >> 2;     // 0..1
    const int wc = wid & 3;      // 0..3

    // ---- staging source pointers (inverse-swizzled global addresses) ----
    const int srow = tid >> 3;                               // 0..63
    const int scol = ((tid & 7) ^ ((tid >> 3) & 7)) << 3;    // elements
    const u16* aSrc[4];
    const u16* bSrc[4];
    #pragma unroll
    for (int q = 0; q < 4; q++) {
        aSrc[q] = A  + (brow + q * 64 + srow) * (long)K + scol;
        bSrc[q] = Bt + (bcol + q * 64 + srow) * (long)K + scol;
    }
    char* dAB = lds + tid * 16;            // + b*32768 + h*16384 + j*8192
    char* dBB = lds + 65536 + tid * 16;

#define ST_A(b,h,kg) do{ \
    gload_lds16(aSrc[2*(h)]   + (kg), dAB + (b)*32768 + (h)*16384); \
    gload_lds16(aSrc[2*(h)+1] + (kg), dAB + (b)*32768 + (h)*16384 + 8192); }while(0)
#define ST_B(b,h,kg) do{ \
    gload_lds16(bSrc[2*(h)]   + (kg), dBB + (b)*32768 + (h)*16384); \
    gload_lds16(bSrc[2*(h)+1] + (kg), dBB + (b)*32768 + (h)*16384 + 8192); }while(0)

    // ---- fragment ds_read addresses (swizzled) ----
    const int swzc = (lane & 7) << 4;
    const int c0 = (((lane >> 4) << 4)) ^ swzc;        // ksub 0
    const int c1 = (64 | ((lane >> 4) << 4)) ^ swzc;   // ksub 1
    const char* Ab = lds + wr * 16384 + (lane & 15) * 128;
    const char* Bb = lds + 65536 + (wc >> 1) * 16384 + ((wc & 1) * 64 + (lane & 15)) * 128;

#define LDA(b,m,ks) (*(const short8*)(Ab + (b)*32768 + (m)*2048 + ((ks)?c1:c0)))
#define LDB(b,n,ks) (*(const short8*)(Bb + (b)*32768 + (n)*2048 + ((ks)?c1:c0)))

#define RD_A4(B_, MB) do{ _Pragma("unroll") for (int m_=0;m_<4;++m_){ aF[m_][0]=LDA(B_,(MB)+m_,0); aF[m_][1]=LDA(B_,(MB)+m_,1);} }while(0)
#define RD_B2(B_, NB, BF) do{ _Pragma("unroll") for (int n_=0;n_<2;++n_){ BF[n_][0]=LDB(B_,(NB)+n_,0); BF[n_][1]=LDB(B_,(NB)+n_,1);} }while(0)

#define QUAD(MB, NB, BF) do{ \
    __builtin_amdgcn_s_setprio(1); \
    _Pragma("unroll") \
    for (int m_ = 0; m_ < 4; ++m_) { \
        _Pragma("unroll") \
        for (int n_ = 0; n_ < 2; ++n_) { \
            acc[(MB)+m_][(NB)+n_] = __builtin_amdgcn_mfma_f32_16x16x32_bf16(aF[m_][0], BF[n_][0], acc[(MB)+m_][(NB)+n_], 0, 0, 0); \
            acc[(MB)+m_][(NB)+n_] = __builtin_amdgcn_mfma_f32_16x16x32_bf16(aF[m_][1], BF[n_][1], acc[(MB)+m_][(NB)+n_], 0, 0, 0); \
        } } \
    __builtin_amdgcn_s_setprio(0); \
}while(0)

    f32x4 acc[8][4];
    #pragma unroll
    for (int m = 0; m < 8; m++)
        #pragma unroll
        for (int n = 0; n < 4; n++)
            acc[m][n] = (f32x4){0.f, 0.f, 0.f, 0.f};

    short8 aF[4][2], bL[2][2], bH[2][2];

    // ---- prologue: buf0 full (tile 0), buf1.B (tile 1) ----
    ST_A(0, 0, 0); ST_A(0, 1, 0); ST_B(0, 0, 0); ST_B(0, 1, 0);
    ST_B(1, 0, 64); ST_B(1, 1, 64);
    asm volatile("s_waitcnt vmcnt(4)" ::: "memory");
    BARRIER();

    const int NIT = K >> 7;    // 2 K-tiles (BK=64) per iteration
    for (int it = 0; it < NIT; ++it) {
        const long k1 = (long)(2 * it + 1) << 6;
        long k2 = (long)(2 * it + 2) << 6; if (k2 > K - 64) k2 = K - 64;
        long k3 = (long)(2 * it + 3) << 6; if (k3 > K - 64) k3 = K - 64;

        // ---- PH1: read buf0 A(m0-3)+B(n0-1); stage buf1.A0@k1; Q00
        RD_A4(0, 0); RD_B2(0, 0, bL);
        ST_A(1, 0, k1);
        asm volatile("s_waitcnt lgkmcnt(8)" ::: "memory");
        BARRIER(); WAIT_LGKM0();
        QUAD(0, 0, bL);
        BARRIER();

        // ---- PH2: read buf0 B(n2-3); stage buf1.A1@k1; Q01
        RD_B2(0, 2, bH);
        ST_A(1, 1, k1);
        BARRIER(); WAIT_LGKM0();
        QUAD(0, 2, bH);
        BARRIER();

        // ---- PH3: read buf0 A(m4-7); stage buf0.B0@k2; Q10
        RD_A4(0, 4);
        ST_B(0, 0, k2);
        BARRIER(); WAIT_LGKM0();
        QUAD(4, 0, bL);
        BARRIER();

        // ---- PH4: stage buf0.B1@k2; vmcnt(4) -> buf1 landed; Q11
        ST_B(0, 1, k2);
        asm volatile("s_waitcnt vmcnt(4)" ::: "memory");
        BARRIER();
        QUAD(4, 2, bH);
        BARRIER();

        // ---- PH5: read buf1 A(m0-3)+B(n0-1); stage buf0.A0@k2; Q00
        RD_A4(1, 0); RD_B2(1, 0, bL);
        ST_A(0, 0, k2);
        asm volatile("s_waitcnt lgkmcnt(8)" ::: "memory");
        BARRIER(); WAIT_LGKM0();
        QUAD(0, 0, bL);
        BARRIER();

        // ---- PH6: read buf1 B(n2-3); stage buf0.A1@k2; Q01
        RD_B2(1, 2, bH);
        ST_A(0, 1, k2);
        BARRIER(); WAIT_LGKM0();
        QUAD(0, 2, bH);
        BARRIER();

        // ---- PH7: read buf1 A(m4-7); stage buf1.B0@k3; Q10
        RD_A4(1, 4);
        ST_B(1, 0, k3);
        BARRIER(); WAIT_LGKM0();
        QUAD(4, 0, bL);
        BARRIER();

        // ---- PH8: stage buf1.B1@k3; vmcnt(4) -> buf0 landed; Q11
        ST_B(1, 1, k3);
        asm volatile("s_waitcnt vmcnt(4)" ::: "memory");
        BARRIER();
        QUAD(4, 2, bH);
        BARRIER();
    }

    asm volatile("s_waitcnt vmcnt(0)" ::: "memory");

    // ---- epilogue ----
    float g = fabsf(gp[0]);
    long crow = brow + wr * 128 + ((lane >> 4) << 2);
    long ccol = bcol + wc * 64 + (lane & 15);
    #pragma unroll
    for (int m = 0; m < 8; m++)
        #pragma unroll
        for (int n = 0; n < 4; n++)
            #pragma unroll
            for (int j = 0; j < 4; j++)
                C[(crow + m * 16 + j) * (long)N + ccol + n * 16] = g * acc[m][n][j];
}

// ---------------- fallback: naive fp32 ----------------
__global__ void fb_gemm(const float* __restrict__ x, const float* __restrict__ w,
                        const float* __restrict__ gp, float* __restrict__ out,
                        int M, int N, int K) {
    __shared__ float xs[16][17];
    __shared__ float ws[16][17];
    int tx = threadIdx.x, ty = threadIdx.y;
    long row = (long)blockIdx.y * 16 + ty;
    long col = (long)blockIdx.x * 16 + tx;
    float s = 0.f;
    for (int k0 = 0; k0 < K; k0 += 16) {
        xs[ty][tx] = x[row * K + k0 + tx];
        float wv = w[(long)(k0 + ty) * N + col];
        ws[ty][tx] = wv > 0.f ? 1.f : (wv < 0.f ? -1.f : 0.f);
        __syncthreads();
        #pragma unroll
        for (int kk = 0; kk < 16; kk++) s += xs[ty][kk] * ws[kk][tx];
        __syncthreads();
    }
    out[row * N + col] = fabsf(gp[0]) * s;
}

extern "C" void kernel_launch(void* const* d_in, const int* in_sizes, int n_in,
                              void* d_out, int out_size, void* d_ws, size_t ws_size,
                              hipStream_t stream) {
    const float* x  = (const float*)d_in[0];
    const float* w  = (const float*)d_in[1];
    const float* gp = (const float*)d_in[2];
    float* out = (float*)d_out;

    const int K = 4096, N = 4096;
    const int M = in_sizes[0] / K;   // 8192

    size_t need = ((size_t)M * K + (size_t)N * K) * sizeof(u16);  // 96 MiB
    bool shape_ok = (M % 256 == 0) && (N % 256 == 0) && (K % 128 == 0);
    if (ws_size >= need && shape_ok) {
        u16* xb = (u16*)d_ws;
        u16* bt = xb + (size_t)M * K;

        long n8 = (long)M * K / 8;
        cvt_x_kernel<<<(int)((n8 + 255) / 256), 256, 0, stream>>>(x, xb, n8);

        dim3 gt(N / 64, K / 64);
        binw_kernel<<<gt, 256, 0, stream>>>(w, bt, K, N);

        int grid = (M / 256) * (N / 256);   // 512
        gemm_bin8<<<grid, 512, 0, stream>>>(xb, bt, gp, out, M, N, K);
    } else {
        dim3 g(N / 16, M / 16), b(16, 16);
        fb_gemm<<<g, b, 0, stream>>>(x, w, gp, out, M, N, K);
    }
}